// Round 5
// baseline (144.311 us; speedup 1.0000x reference)
//
#include <hip/hip_runtime.h>

#define BB 8
#define S_ENC 256
#define S_DEC 128
#define DM 512
#define UN 512

typedef __attribute__((ext_vector_type(8))) __bf16 bf16x8;
typedef __attribute__((ext_vector_type(4))) float f32x4;

// pack two fp32 into two bf16 (truncation; residual captured by pack_lo)
__device__ inline unsigned int pack_hi(float x0, float x1) {
    return __builtin_amdgcn_perm(__float_as_uint(x1), __float_as_uint(x0), 0x07060302u);
}
__device__ inline unsigned int pack_lo(float x0, float x1) {
    float h0 = __uint_as_float(__float_as_uint(x0) & 0xFFFF0000u);
    float h1 = __uint_as_float(__float_as_uint(x1) & 0xFFFF0000u);
    return __builtin_amdgcn_perm(__float_as_uint(x1 - h1), __float_as_uint(x0 - h0), 0x07060302u);
}

// ---------------------------------------------------------------------------
// Kernel 0: transpose + bf16-split W:  WT_hi/lo[u][d] <- W[d][u]
// ---------------------------------------------------------------------------
__global__ __launch_bounds__(256) void prep_w(
    const float* __restrict__ Wenc, const float* __restrict__ Wdec,
    unsigned short* __restrict__ Weh, unsigned short* __restrict__ Wel,
    unsigned short* __restrict__ Wdh, unsigned short* __restrict__ Wdl)
{
    __shared__ float L[64][68];
    const int bid = blockIdx.x;
    const float* W = (bid < 64) ? Wenc : Wdec;
    unsigned short* Th = (bid < 64) ? Weh : Wdh;
    unsigned short* Tl = (bid < 64) ? Wel : Wdl;
    const int tb = bid & 63;
    const int d0 = (tb >> 3) << 6, u0v = (tb & 7) << 6;
    const int t = threadIdx.x;
    {
        const int c4 = (t & 15) << 2;
#pragma unroll
        for (int i = 0; i < 4; ++i) {
            int row = (i << 4) + (t >> 4);
            *(float4*)&L[row][c4] = *(const float4*)&W[(size_t)(d0 + row) * 512 + u0v + c4];
        }
    }
    __syncthreads();
    const int u = t >> 2, dg = t & 3;
    unsigned int hw[8], lw[8];
#pragma unroll
    for (int j = 0; j < 8; ++j) {
        float x0 = L[(dg << 4) + (j << 1) + 0][u];
        float x1 = L[(dg << 4) + (j << 1) + 1][u];
        hw[j] = pack_hi(x0, x1);
        lw[j] = pack_lo(x0, x1);
    }
    size_t ob = (size_t)(u0v + u) * 512 + d0 + (dg << 4);
    *(uint4*)&Th[ob]     = make_uint4(hw[0], hw[1], hw[2], hw[3]);
    *(uint4*)&Th[ob + 8] = make_uint4(hw[4], hw[5], hw[6], hw[7]);
    *(uint4*)&Tl[ob]     = make_uint4(lw[0], lw[1], lw[2], lw[3]);
    *(uint4*)&Tl[ob + 8] = make_uint4(lw[4], lw[5], lw[6], lw[7]);
}

// ---------------------------------------------------------------------------
// Kernel 1: projections via split-bf16 MFMA (AhBh + AhBl + AlBh).
// 64x64 tile, 256 thr = 2x2 waves of 32x32, BK=32.
// XCD-swizzled: batch b == bid&7 == XCD id, so d_encT4/d_dec writes land in
// the L2 of the XCD whose attend blocks will read them.
// ---------------------------------------------------------------------------
__global__ __launch_bounds__(256) void proj_kernel(
    const float* __restrict__ enc, const float* __restrict__ dec,
    const unsigned short* __restrict__ Weh, const unsigned short* __restrict__ Wel,
    const unsigned short* __restrict__ Wdh, const unsigned short* __restrict__ Wdl,
    const float* __restrict__ bias_enc, const float* __restrict__ bias_dec,
    float* __restrict__ d_encT4,   // [B][128][256][4], pre-scaled by 2*log2(e)
    float* __restrict__ d_dec)     // [1024][512]
{
    __shared__ unsigned short Ah[64][48], Al[64][48], Bh[64][48], Bl[64][48];

    const float Cs = 2.8853900817779268f;   // 2*log2(e)

    const int bid = blockIdx.x;
    const bool is_enc = (bid < 256);
    const int t = threadIdx.x;
    const int r = t >> 2, qc = t & 3;        // staging: row 0..63, 8-wide k-chunk

    const float* conv_src; int conv_row0;
    const unsigned short *cp_hi, *cp_lo; int cp_row0;
    int u0, e0, b, r0 = 0;
    if (is_enc) {
        b = bid & 7;                          // XCD-local batch
        int sub = (bid >> 3) & 31;
        u0 = (sub >> 2) << 6;
        e0 = (sub & 3) << 6;
        conv_src = enc; conv_row0 = (b << 8) + e0;
        cp_hi = Weh; cp_lo = Wel; cp_row0 = u0;
    } else {
        int bid2 = bid - 256;                 // 0..127
        int ut = bid2 >> 4;                   // 0..7
        int rt = ((bid2 & 7) << 1) | ((bid2 >> 3) & 1);  // row-tile; b = rt>>1 = bid2&7
        r0 = rt << 6;
        u0 = ut << 6;
        conv_src = dec; conv_row0 = r0;
        cp_hi = Wdh; cp_lo = Wdl; cp_row0 = u0;
        e0 = 0; b = 0;
    }

    unsigned short (*CvH)[48] = is_enc ? Bh : Ah;   // converted fp32 operand
    unsigned short (*CvL)[48] = is_enc ? Bl : Al;
    unsigned short (*CpH)[48] = is_enc ? Ah : Bh;   // pre-split W operand
    unsigned short (*CpL)[48] = is_enc ? Al : Bl;

    const float* cv_p          = &conv_src[(size_t)(conv_row0 + r) * 512 + (qc << 3)];
    const unsigned short* ch_p = &cp_hi[(size_t)(cp_row0 + r) * 512 + (qc << 3)];
    const unsigned short* cl_p = &cp_lo[(size_t)(cp_row0 + r) * 512 + (qc << 3)];

    const int lane = t & 63, wv = t >> 6;
    const int wy = wv >> 1, wx = wv & 1;
    const int frow = lane & 15, quad = lane >> 4;

    f32x4 acc[2][2] = {{{0.f,0.f,0.f,0.f},{0.f,0.f,0.f,0.f}},
                       {{0.f,0.f,0.f,0.f},{0.f,0.f,0.f,0.f}}};

    // prologue prefetch (k0 = 0)
    float4 nx0 = *(const float4*)cv_p;
    float4 nx1 = *(const float4*)(cv_p + 4);
    uint4  nwh = *(const uint4*)ch_p;
    uint4  nwl = *(const uint4*)cl_p;

    for (int k0 = 0; k0 < 512; k0 += 32) {
        float4 x0 = nx0, x1 = nx1;
        uint4 wh = nwh, wl = nwl;
        unsigned int h0 = pack_hi(x0.x, x0.y), l0 = pack_lo(x0.x, x0.y);
        unsigned int h1 = pack_hi(x0.z, x0.w), l1 = pack_lo(x0.z, x0.w);
        unsigned int h2 = pack_hi(x1.x, x1.y), l2 = pack_lo(x1.x, x1.y);
        unsigned int h3 = pack_hi(x1.z, x1.w), l3 = pack_lo(x1.z, x1.w);
        __syncthreads();                      // prior iteration's reads done
        *(uint4*)&CvH[r][qc << 3] = make_uint4(h0, h1, h2, h3);
        *(uint4*)&CvL[r][qc << 3] = make_uint4(l0, l1, l2, l3);
        *(uint4*)&CpH[r][qc << 3] = wh;
        *(uint4*)&CpL[r][qc << 3] = wl;
        __syncthreads();
        if (k0 + 32 < 512) {                  // prefetch next tile during MFMA
            nx0 = *(const float4*)(cv_p + k0 + 32);
            nx1 = *(const float4*)(cv_p + k0 + 36);
            nwh = *(const uint4*)(ch_p + k0 + 32);
            nwl = *(const uint4*)(cl_p + k0 + 32);
        }
        bf16x8 ah[2], al[2], bh[2], bl[2];
#pragma unroll
        for (int f = 0; f < 2; ++f) {
            ah[f] = *(const bf16x8*)&Ah[(wy << 5) + (f << 4) + frow][quad << 3];
            al[f] = *(const bf16x8*)&Al[(wy << 5) + (f << 4) + frow][quad << 3];
            bh[f] = *(const bf16x8*)&Bh[(wx << 5) + (f << 4) + frow][quad << 3];
            bl[f] = *(const bf16x8*)&Bl[(wx << 5) + (f << 4) + frow][quad << 3];
        }
#pragma unroll
        for (int fm = 0; fm < 2; ++fm)
#pragma unroll
            for (int fn = 0; fn < 2; ++fn) {
                acc[fm][fn] = __builtin_amdgcn_mfma_f32_16x16x32_bf16(ah[fm], bh[fn], acc[fm][fn], 0, 0, 0);
                acc[fm][fn] = __builtin_amdgcn_mfma_f32_16x16x32_bf16(ah[fm], bl[fn], acc[fm][fn], 0, 0, 0);
                acc[fm][fn] = __builtin_amdgcn_mfma_f32_16x16x32_bf16(al[fm], bh[fn], acc[fm][fn], 0, 0, 0);
            }
    }

    // epilogue: C/D layout col = lane&15, row = quad*4 + reg
    if (is_enc) {
#pragma unroll
        for (int fm = 0; fm < 2; ++fm)
#pragma unroll
            for (int fn = 0; fn < 2; ++fn) {
                int u_base = u0 + (wy << 5) + (fm << 4) + (quad << 2);  // +reg = u
                int e      = e0 + (wx << 5) + (fn << 4) + frow;
                float4 bi = *(const float4*)&bias_enc[u_base];
                float4 o = make_float4((acc[fm][fn][0] + bi.x) * Cs,
                                       (acc[fm][fn][1] + bi.y) * Cs,
                                       (acc[fm][fn][2] + bi.z) * Cs,
                                       (acc[fm][fn][3] + bi.w) * Cs);
                size_t idx = ((size_t)((b << 7) + (u_base >> 2)) << 10) + ((size_t)e << 2);
                *(float4*)&d_encT4[idx] = o;
            }
    } else {
#pragma unroll
        for (int fm = 0; fm < 2; ++fm)
#pragma unroll
            for (int fn = 0; fn < 2; ++fn) {
                int row_b = r0 + (wy << 5) + (fm << 4) + (quad << 2);
                int u_col = u0 + (wx << 5) + (fn << 4) + frow;
                float bi = bias_dec[u_col];
#pragma unroll
                for (int g = 0; g < 4; ++g)
                    d_dec[(size_t)(row_b + g) * 512 + u_col] = acc[fm][fn][g] + bi;
            }
    }
}

// ---------------------------------------------------------------------------
// Kernel 2: fused scores + softmax + context. Trans-free score loop.
// XCD-swizzled: b = bid & 7, so all 32 blocks of batch b run on XCD b and
// d_encT4[b] (512 KB) + enc[b] (512 KB) stay resident in that XCD's 4 MB L2.
// ---------------------------------------------------------------------------
#define TA1 0.69314718056f
#define TA2 0.24022650700f
#define TA3 0.05550410866f
#define TA4 0.00961812911f
#define TA5 0.00133335581f

__device__ inline void score_u(float t, const float* Gp, float w,
                               float& a0, float& a1, float& a2, float& a3) {
    float n = rintf(t);
    float f = t - n;
    int  i  = (int)n;
    float p = fmaf(f, TA5, TA4);
    p = fmaf(f, p, TA3);
    p = fmaf(f, p, TA2);
    p = fmaf(f, p, TA1);
    p = fmaf(f, p, 1.0f);
    float E = __uint_as_float(__float_as_uint(p) + (((unsigned)i) << 23));
    float4 G = *(const float4*)Gp;   // wave-uniform broadcast
    float D0 = fmaf(E, G.x, 1.0f);
    float D1 = fmaf(E, G.y, 1.0f);
    float D2 = fmaf(E, G.z, 1.0f);
    float D3 = fmaf(E, G.w, 1.0f);
    float s0 = __uint_as_float(0x7EF311C3u - __float_as_uint(D0));
    float s1 = __uint_as_float(0x7EF311C3u - __float_as_uint(D1));
    float s2 = __uint_as_float(0x7EF311C3u - __float_as_uint(D2));
    float s3 = __uint_as_float(0x7EF311C3u - __float_as_uint(D3));
    s0 *= fmaf(-D0, s0, 2.0f);  s0 *= fmaf(-D0, s0, 2.0f);
    s1 *= fmaf(-D1, s1, 2.0f);  s1 *= fmaf(-D1, s1, 2.0f);
    s2 *= fmaf(-D2, s2, 2.0f);  s2 *= fmaf(-D2, s2, 2.0f);
    s3 *= fmaf(-D3, s3, 2.0f);  s3 *= fmaf(-D3, s3, 2.0f);
    a0 = fmaf(w, s0, a0);
    a1 = fmaf(w, s1, a1);
    a2 = fmaf(w, s2, a2);
    a3 = fmaf(w, s3, a3);
}

__global__ __launch_bounds__(1024) void attend_kernel(
    const float* __restrict__ enc,      // [B, 256, 512]
    const float* __restrict__ d_encT4,  // [B][128][256][4], pre-scaled
    const float* __restrict__ d_dec,    // [B*128, 512]
    const float* __restrict__ Wscore,   // [512]
    float* __restrict__ out)            // [B, 128, 512]
{
    __shared__ float Gq[UN][4];          // 2^(dd*C) per [u][q]
    __shared__ float wsc[UN];
    __shared__ float accs[4][4][256];    // [u-quarter][q][e]
    __shared__ float wT[256][4];         // softmax weights [e][q]

    const float C = 2.8853900817779268f;
    const float LOG2E = 1.4426950408889634f;

    const int bid = blockIdx.x;
    const int b = bid & 7;               // XCD-local batch
    const int q0 = ((bid >> 3) & 31) << 2;
    const int tid = threadIdx.x;

    {
        int q  = tid >> 8;
        int u2 = (tid & 255) << 1;
        float2 v = *(const float2*)&d_dec[((size_t)(b * S_DEC) + q0 + q) * UN + u2];
        Gq[u2 + 0][q] = __builtin_amdgcn_exp2f(v.x * C);
        Gq[u2 + 1][q] = __builtin_amdgcn_exp2f(v.y * C);
    }
    if (tid < 128) {
        *(float4*)&wsc[tid << 2] = *(const float4*)&Wscore[tid << 2];
    }
    __syncthreads();

    const int wv = tid >> 6, lane = tid & 63;
    const int e  = ((wv & 3) << 6) + lane;
    const int uq = wv >> 2, u0 = uq << 7;     // 128 u per wave = 32 groups of 4

    float a0 = 0.f, a1 = 0.f, a2 = 0.f, a3 = 0.f;
    const float4* dptr = (const float4*)d_encT4 +
                         (((size_t)(b << 7) + (u0 >> 2)) << 8) + e;
    float4 de = dptr[0];
    for (int g = 0; g < 32; ++g) {
        int gn = (g < 31) ? (g + 1) : 31;
        float4 de_n = dptr[(size_t)gn << 8];       // prefetch next group
        int u = u0 + (g << 2);
        float4 w4 = *(const float4*)&wsc[u];
        score_u(de.x, &Gq[u + 0][0], w4.x, a0, a1, a2, a3);
        score_u(de.y, &Gq[u + 1][0], w4.y, a0, a1, a2, a3);
        score_u(de.z, &Gq[u + 2][0], w4.z, a0, a1, a2, a3);
        score_u(de.w, &Gq[u + 3][0], w4.w, a0, a1, a2, a3);
        de = de_n;
    }
    accs[uq][0][e] = a0;
    accs[uq][1][e] = a1;
    accs[uq][2][e] = a2;
    accs[uq][3][e] = a3;
    __syncthreads();

    if (wv < 4) {
        const int q = wv;
        float l[4];
        float m = -1e30f;
#pragma unroll
        for (int i = 0; i < 4; ++i) {
            int ee = lane + (i << 6);
            float a = accs[0][q][ee] + accs[1][q][ee] +
                      accs[2][q][ee] + accs[3][q][ee];
            l[i] = -2.f * a;
            m = fmaxf(m, l[i]);
        }
#pragma unroll
        for (int mk = 32; mk >= 1; mk >>= 1) m = fmaxf(m, __shfl_xor(m, mk, 64));
        float p[4];
        float s = 0.f;
#pragma unroll
        for (int i = 0; i < 4; ++i) {
            p[i] = __builtin_amdgcn_exp2f((l[i] - m) * LOG2E);
            s += p[i];
        }
#pragma unroll
        for (int mk = 32; mk >= 1; mk >>= 1) s += __shfl_xor(s, mk, 64);
        float inv = __builtin_amdgcn_rcpf(s);
#pragma unroll
        for (int i = 0; i < 4; ++i) wT[lane + (i << 6)][q] = p[i] * inv;
    }
    __syncthreads();

    {
        const int q  = tid >> 8;
        const int d2 = (tid & 255) << 1;
        float c0_ = 0.f, c1_ = 0.f;
        const float* ep = enc + ((size_t)b * S_ENC) * DM + d2;
#pragma unroll 4
        for (int ee = 0; ee < 256; ++ee) {
            float2 x = *(const float2*)(ep + ((size_t)ee << 9));
            float w = wT[ee][q];
            c0_ = fmaf(w, x.x, c0_);
            c1_ = fmaf(w, x.y, c1_);
        }
        float* op = out + ((size_t)(b * S_DEC) + q0 + q) * DM + d2;
        *(float2*)op = make_float2(c0_, c1_);
    }
}

// ---------------------------------------------------------------------------
extern "C" void kernel_launch(void* const* d_in, const int* in_sizes, int n_in,
                              void* d_out, int out_size, void* d_ws, size_t ws_size,
                              hipStream_t stream) {
    const float* enc      = (const float*)d_in[0];
    const float* dec      = (const float*)d_in[1];
    const float* Wenc     = (const float*)d_in[2];
    const float* Wdec     = (const float*)d_in[3];
    const float* Wscore   = (const float*)d_in[4];
    const float* bias_enc = (const float*)d_in[5];
    const float* bias_dec = (const float*)d_in[6];
    // d_in[7] = bias_score: constant shift, cancelled by softmax.
    float* out = (float*)d_out;

    float* ws = (float*)d_ws;
    float* d_encT4 = ws;                               // 1,048,576 floats (4 MB)
    float* d_decP  = ws + 1048576;                     // 524,288 floats (2 MB)
    unsigned short* Weh = (unsigned short*)(ws + 1048576 + 524288);
    unsigned short* Wel = Weh + 262144;                // 4 x 512 KB = 2 MB
    unsigned short* Wdh = Wel + 262144;
    unsigned short* Wdl = Wdh + 262144;                // total ws use: 8 MB

    prep_w<<<128, 256, 0, stream>>>(Wenc, Wdec, Weh, Wel, Wdh, Wdl);
    proj_kernel<<<384, 256, 0, stream>>>(enc, dec, Weh, Wel, Wdh, Wdl,
                                         bias_enc, bias_dec, d_encT4, d_decP);
    attend_kernel<<<256, 1024, 0, stream>>>(enc, d_encT4, d_decP, Wscore, out);
}

// Round 6
// 133.360 us; speedup vs baseline: 1.0821x; 1.0821x over previous
//
#include <hip/hip_runtime.h>

#define BB 8
#define S_ENC 256
#define S_DEC 128
#define UN 512

typedef __attribute__((ext_vector_type(8))) __bf16 bf16x8;
typedef __attribute__((ext_vector_type(4))) float f32x4;

// pack two fp32 into two bf16 (truncation; residual captured by pack_lo)
__device__ inline unsigned int pack_hi(float x0, float x1) {
    return __builtin_amdgcn_perm(__float_as_uint(x1), __float_as_uint(x0), 0x07060302u);
}
__device__ inline unsigned int pack_lo(float x0, float x1) {
    float h0 = __uint_as_float(__float_as_uint(x0) & 0xFFFF0000u);
    float h1 = __uint_as_float(__float_as_uint(x1) & 0xFFFF0000u);
    return __builtin_amdgcn_perm(__float_as_uint(x1 - h1), __float_as_uint(x0 - h0), 0x07060302u);
}

// ---------------------------------------------------------------------------
// Kernel 0: transpose + bf16-split W:  WT_hi/lo[u][d] <- W[d][u]
// LDS stride 65 (odd) -> column reads are <=2-way bank aliased (free).
// ---------------------------------------------------------------------------
__global__ __launch_bounds__(256) void prep_w(
    const float* __restrict__ Wenc, const float* __restrict__ Wdec,
    unsigned short* __restrict__ Weh, unsigned short* __restrict__ Wel,
    unsigned short* __restrict__ Wdh, unsigned short* __restrict__ Wdl)
{
    __shared__ float L[64][65];
    const int bid = blockIdx.x;
    const float* W = (bid < 64) ? Wenc : Wdec;
    unsigned short* Th = (bid < 64) ? Weh : Wdh;
    unsigned short* Tl = (bid < 64) ? Wel : Wdl;
    const int tb = bid & 63;
    const int d0 = (tb >> 3) << 6, u0v = (tb & 7) << 6;
    const int t = threadIdx.x;
    {
        const int c4 = (t & 15) << 2;
#pragma unroll
        for (int i = 0; i < 4; ++i) {
            int row = (i << 4) + (t >> 4);
            float4 v = *(const float4*)&W[(size_t)(d0 + row) * 512 + u0v + c4];
            L[row][c4 + 0] = v.x;
            L[row][c4 + 1] = v.y;
            L[row][c4 + 2] = v.z;
            L[row][c4 + 3] = v.w;
        }
    }
    __syncthreads();
    const int u = t >> 2, dg = t & 3;
    unsigned int hw[8], lw[8];
#pragma unroll
    for (int j = 0; j < 8; ++j) {
        float x0 = L[(dg << 4) + (j << 1) + 0][u];
        float x1 = L[(dg << 4) + (j << 1) + 1][u];
        hw[j] = pack_hi(x0, x1);
        lw[j] = pack_lo(x0, x1);
    }
    size_t ob = (size_t)(u0v + u) * 512 + d0 + (dg << 4);
    *(uint4*)&Th[ob]     = make_uint4(hw[0], hw[1], hw[2], hw[3]);
    *(uint4*)&Th[ob + 8] = make_uint4(hw[4], hw[5], hw[6], hw[7]);
    *(uint4*)&Tl[ob]     = make_uint4(lw[0], lw[1], lw[2], lw[3]);
    *(uint4*)&Tl[ob + 8] = make_uint4(lw[4], lw[5], lw[6], lw[7]);
}

// ---------------------------------------------------------------------------
// Kernel 1: projections via split-bf16 MFMA, NO LDS, NO barriers.
// Both operands are K-contiguous 16B fragments loaded straight from global
// (W^T pre-split planes; enc/dec fp32 rows converted in-register).
// 64x64 tile, 256 thr = 2x2 waves of 32x32, BK=32, 1-step register prefetch.
//   enc blocks (bid<256): A=W^T rows u, B=enc rows e -> d_encT4 (u-packed x4,
//       scaled by 2*log2e, bias added)
//   dec blocks: A=dec rows, B=Wd^T rows u -> Gt[(b,q)][u] = 2^((dd+bias)*C)
// ---------------------------------------------------------------------------
__global__ __launch_bounds__(256) void proj_kernel(
    const float* __restrict__ enc, const float* __restrict__ dec,
    const unsigned short* __restrict__ Weh, const unsigned short* __restrict__ Wel,
    const unsigned short* __restrict__ Wdh, const unsigned short* __restrict__ Wdl,
    const float* __restrict__ bias_enc, const float* __restrict__ bias_dec,
    float* __restrict__ d_encT4,   // [B][128][256][4]
    float* __restrict__ Gt)        // [B*128][512]
{
    const float Cs = 2.8853900817779268f;   // 2*log2(e)
    const int bid = blockIdx.x;
    const int t = threadIdx.x;
    const int lane = t & 63, wv = t >> 6;
    const int wy = wv >> 1, wx = wv & 1;
    const int frow = lane & 15, quad = lane >> 4;
    const int ko = quad << 3;

    f32x4 acc[2][2] = {{{0.f,0.f,0.f,0.f},{0.f,0.f,0.f,0.f}},
                       {{0.f,0.f,0.f,0.f},{0.f,0.f,0.f,0.f}}};

    if (bid < 256) {
        // ---------------- encoder projection ----------------
        const int b = bid & 7, sub = bid >> 3;
        const int u0 = (sub >> 2) << 6, e0 = (sub & 3) << 6;
        const unsigned short *aph[2], *apl[2];
        const float* bp[2];
#pragma unroll
        for (int fm = 0; fm < 2; ++fm) {
            int row = u0 + (wy << 5) + (fm << 4) + frow;
            aph[fm] = Weh + (size_t)row * 512 + ko;
            apl[fm] = Wel + (size_t)row * 512 + ko;
        }
#pragma unroll
        for (int fn = 0; fn < 2; ++fn) {
            int row = (b << 8) + e0 + (wx << 5) + (fn << 4) + frow;
            bp[fn] = enc + (size_t)row * 512 + ko;
        }
        bf16x8 nah[2], nal[2];
        float4 nb0[2], nb1[2];
#pragma unroll
        for (int f = 0; f < 2; ++f) {
            nah[f] = *(const bf16x8*)(aph[f]);
            nal[f] = *(const bf16x8*)(apl[f]);
            nb0[f] = *(const float4*)(bp[f]);
            nb1[f] = *(const float4*)(bp[f] + 4);
        }
        for (int k0 = 0; k0 < 512; k0 += 32) {
            bf16x8 ah[2] = {nah[0], nah[1]}, al[2] = {nal[0], nal[1]};
            float4 c0[2] = {nb0[0], nb0[1]}, c1[2] = {nb1[0], nb1[1]};
            if (k0 + 32 < 512) {
#pragma unroll
                for (int f = 0; f < 2; ++f) {
                    nah[f] = *(const bf16x8*)(aph[f] + k0 + 32);
                    nal[f] = *(const bf16x8*)(apl[f] + k0 + 32);
                    nb0[f] = *(const float4*)(bp[f] + k0 + 32);
                    nb1[f] = *(const float4*)(bp[f] + k0 + 36);
                }
            }
            bf16x8 bh[2], bl[2];
#pragma unroll
            for (int f = 0; f < 2; ++f) {
                union { unsigned int w[4]; bf16x8 v; } H, L;
                H.w[0] = pack_hi(c0[f].x, c0[f].y);
                H.w[1] = pack_hi(c0[f].z, c0[f].w);
                H.w[2] = pack_hi(c1[f].x, c1[f].y);
                H.w[3] = pack_hi(c1[f].z, c1[f].w);
                L.w[0] = pack_lo(c0[f].x, c0[f].y);
                L.w[1] = pack_lo(c0[f].z, c0[f].w);
                L.w[2] = pack_lo(c1[f].x, c1[f].y);
                L.w[3] = pack_lo(c1[f].z, c1[f].w);
                bh[f] = H.v; bl[f] = L.v;
            }
#pragma unroll
            for (int fm = 0; fm < 2; ++fm)
#pragma unroll
                for (int fn = 0; fn < 2; ++fn) {
                    acc[fm][fn] = __builtin_amdgcn_mfma_f32_16x16x32_bf16(ah[fm], bh[fn], acc[fm][fn], 0, 0, 0);
                    acc[fm][fn] = __builtin_amdgcn_mfma_f32_16x16x32_bf16(ah[fm], bl[fn], acc[fm][fn], 0, 0, 0);
                    acc[fm][fn] = __builtin_amdgcn_mfma_f32_16x16x32_bf16(al[fm], bh[fn], acc[fm][fn], 0, 0, 0);
                }
        }
        // epilogue: C row = u (quad*4+reg), col = e (frow)
#pragma unroll
        for (int fm = 0; fm < 2; ++fm)
#pragma unroll
            for (int fn = 0; fn < 2; ++fn) {
                int u_base = u0 + (wy << 5) + (fm << 4) + (quad << 2);
                int e      = e0 + (wx << 5) + (fn << 4) + frow;
                float4 bi = *(const float4*)&bias_enc[u_base];
                float4 o = make_float4((acc[fm][fn][0] + bi.x) * Cs,
                                       (acc[fm][fn][1] + bi.y) * Cs,
                                       (acc[fm][fn][2] + bi.z) * Cs,
                                       (acc[fm][fn][3] + bi.w) * Cs);
                size_t idx = ((size_t)((b << 7) + (u_base >> 2)) << 10) + ((size_t)e << 2);
                *(float4*)&d_encT4[idx] = o;
            }
    } else {
        // ---------------- decoder projection -> G table ----------------
        const int bid2 = bid - 256;
        const int b = bid2 & 7;
        const int ut = (bid2 >> 3) & 7;
        const int rh = bid2 >> 6;
        const int r0 = (b << 7) + (rh << 6);     // flattened (b,q) row base
        const int u0v = ut << 6;
        const float* ap[2];
        const unsigned short *bph[2], *bpl[2];
#pragma unroll
        for (int fm = 0; fm < 2; ++fm) {
            int row = r0 + (wy << 5) + (fm << 4) + frow;
            ap[fm] = dec + (size_t)row * 512 + ko;
        }
#pragma unroll
        for (int fn = 0; fn < 2; ++fn) {
            int row = u0v + (wx << 5) + (fn << 4) + frow;
            bph[fn] = Wdh + (size_t)row * 512 + ko;
            bpl[fn] = Wdl + (size_t)row * 512 + ko;
        }
        bf16x8 nbh[2], nbl[2];
        float4 na0[2], na1[2];
#pragma unroll
        for (int f = 0; f < 2; ++f) {
            nbh[f] = *(const bf16x8*)(bph[f]);
            nbl[f] = *(const bf16x8*)(bpl[f]);
            na0[f] = *(const float4*)(ap[f]);
            na1[f] = *(const float4*)(ap[f] + 4);
        }
        for (int k0 = 0; k0 < 512; k0 += 32) {
            bf16x8 wh[2] = {nbh[0], nbh[1]}, wl[2] = {nbl[0], nbl[1]};
            float4 c0[2] = {na0[0], na0[1]}, c1[2] = {na1[0], na1[1]};
            if (k0 + 32 < 512) {
#pragma unroll
                for (int f = 0; f < 2; ++f) {
                    nbh[f] = *(const bf16x8*)(bph[f] + k0 + 32);
                    nbl[f] = *(const bf16x8*)(bpl[f] + k0 + 32);
                    na0[f] = *(const float4*)(ap[f] + k0 + 32);
                    na1[f] = *(const float4*)(ap[f] + k0 + 36);
                }
            }
            bf16x8 ah[2], al[2];
#pragma unroll
            for (int f = 0; f < 2; ++f) {
                union { unsigned int w[4]; bf16x8 v; } H, L;
                H.w[0] = pack_hi(c0[f].x, c0[f].y);
                H.w[1] = pack_hi(c0[f].z, c0[f].w);
                H.w[2] = pack_hi(c1[f].x, c1[f].y);
                H.w[3] = pack_hi(c1[f].z, c1[f].w);
                L.w[0] = pack_lo(c0[f].x, c0[f].y);
                L.w[1] = pack_lo(c0[f].z, c0[f].w);
                L.w[2] = pack_lo(c1[f].x, c1[f].y);
                L.w[3] = pack_lo(c1[f].z, c1[f].w);
                ah[f] = H.v; al[f] = L.v;
            }
#pragma unroll
            for (int fm = 0; fm < 2; ++fm)
#pragma unroll
                for (int fn = 0; fn < 2; ++fn) {
                    acc[fm][fn] = __builtin_amdgcn_mfma_f32_16x16x32_bf16(ah[fm], wh[fn], acc[fm][fn], 0, 0, 0);
                    acc[fm][fn] = __builtin_amdgcn_mfma_f32_16x16x32_bf16(al[fm], wh[fn], acc[fm][fn], 0, 0, 0);
                    acc[fm][fn] = __builtin_amdgcn_mfma_f32_16x16x32_bf16(ah[fm], wl[fn], acc[fm][fn], 0, 0, 0);
                }
        }
        // epilogue: G = 2^((dd+bias)*Cs); rows=(b,q), cols=u
#pragma unroll
        for (int fm = 0; fm < 2; ++fm)
#pragma unroll
            for (int fn = 0; fn < 2; ++fn) {
                int rowb = r0 + (wy << 5) + (fm << 4) + (quad << 2);
                int u    = u0v + (wx << 5) + (fn << 4) + frow;
                float bi = bias_dec[u];
#pragma unroll
                for (int g = 0; g < 4; ++g)
                    Gt[(size_t)(rowb + g) * 512 + u] =
                        __builtin_amdgcn_exp2f((acc[fm][fn][g] + bi) * Cs);
            }
    }
}

// ---------------------------------------------------------------------------
// Kernel 2: fused scores + softmax + context.
// Score loop: zero LDS; G & Wscore via wave-uniform scalar loads (prefetched),
// de via vector float4 (prefetched). s = rcp(1 + E*G), E = exp2(de').
// Context: each wave covers one e-quarter -> enc read 1x; LDS partial reduce.
// ---------------------------------------------------------------------------
__global__ __launch_bounds__(1024) void attend_kernel(
    const float* __restrict__ enc,      // [B, 256, 512]
    const float* __restrict__ d_encT4,  // [B][128][256][4], pre-scaled
    const float* __restrict__ Gt,       // [B*128][512] = 2^(dd*C)
    const float* __restrict__ Wscore,   // [512]
    float* __restrict__ out)            // [B, 128, 512]
{
    __shared__ float smem[8192];         // score accs (16 KB) / ctx scratch (32 KB)
    __shared__ float wT[256][4];         // softmax weights [e][q]

    const float LOG2E = 1.4426950408889634f;

    const int bid = blockIdx.x;
    const int b = bid & 7;                      // XCD-local batch
    const int q0 = ((bid >> 3) & 31) << 2;
    const int tid = threadIdx.x;
    const int wv = tid >> 6, lane = tid & 63;

    // ---------------- scores ----------------
    const int e  = ((wv & 3) << 6) + lane;
    const int uq = wv >> 2;
    const int u0 = __builtin_amdgcn_readfirstlane(uq << 7);

    const float* Gb = Gt + ((size_t)((b << 7) + q0) << 9);
    const float4* dptr = (const float4*)d_encT4 +
                         (((size_t)(b << 7) + (u0 >> 2)) << 8) + e;

    float a0 = 0.f, a1 = 0.f, a2 = 0.f, a3 = 0.f;
    float4 de = dptr[0];
    float4 g0 = *(const float4*)(Gb + u0);
    float4 g1 = *(const float4*)(Gb + 512 + u0);
    float4 g2 = *(const float4*)(Gb + 1024 + u0);
    float4 g3 = *(const float4*)(Gb + 1536 + u0);
    float4 w4 = *(const float4*)(Wscore + u0);
    for (int g = 0; g < 32; ++g) {
        float4 cg0 = g0, cg1 = g1, cg2 = g2, cg3 = g3, cw = w4;
        float4 cde = de;
        if (g < 31) {
            const int un = u0 + ((g + 1) << 2);
            g0 = *(const float4*)(Gb + un);
            g1 = *(const float4*)(Gb + 512 + un);
            g2 = *(const float4*)(Gb + 1024 + un);
            g3 = *(const float4*)(Gb + 1536 + un);
            w4 = *(const float4*)(Wscore + un);
            de = dptr[(size_t)(g + 1) << 8];
        }
        float E;
        E = __builtin_amdgcn_exp2f(cde.x);
        a0 = fmaf(cw.x, __builtin_amdgcn_rcpf(fmaf(E, cg0.x, 1.f)), a0);
        a1 = fmaf(cw.x, __builtin_amdgcn_rcpf(fmaf(E, cg1.x, 1.f)), a1);
        a2 = fmaf(cw.x, __builtin_amdgcn_rcpf(fmaf(E, cg2.x, 1.f)), a2);
        a3 = fmaf(cw.x, __builtin_amdgcn_rcpf(fmaf(E, cg3.x, 1.f)), a3);
        E = __builtin_amdgcn_exp2f(cde.y);
        a0 = fmaf(cw.y, __builtin_amdgcn_rcpf(fmaf(E, cg0.y, 1.f)), a0);
        a1 = fmaf(cw.y, __builtin_amdgcn_rcpf(fmaf(E, cg1.y, 1.f)), a1);
        a2 = fmaf(cw.y, __builtin_amdgcn_rcpf(fmaf(E, cg2.y, 1.f)), a2);
        a3 = fmaf(cw.y, __builtin_amdgcn_rcpf(fmaf(E, cg3.y, 1.f)), a3);
        E = __builtin_amdgcn_exp2f(cde.z);
        a0 = fmaf(cw.z, __builtin_amdgcn_rcpf(fmaf(E, cg0.z, 1.f)), a0);
        a1 = fmaf(cw.z, __builtin_amdgcn_rcpf(fmaf(E, cg1.z, 1.f)), a1);
        a2 = fmaf(cw.z, __builtin_amdgcn_rcpf(fmaf(E, cg2.z, 1.f)), a2);
        a3 = fmaf(cw.z, __builtin_amdgcn_rcpf(fmaf(E, cg3.z, 1.f)), a3);
        E = __builtin_amdgcn_exp2f(cde.w);
        a0 = fmaf(cw.w, __builtin_amdgcn_rcpf(fmaf(E, cg0.w, 1.f)), a0);
        a1 = fmaf(cw.w, __builtin_amdgcn_rcpf(fmaf(E, cg1.w, 1.f)), a1);
        a2 = fmaf(cw.w, __builtin_amdgcn_rcpf(fmaf(E, cg2.w, 1.f)), a2);
        a3 = fmaf(cw.w, __builtin_amdgcn_rcpf(fmaf(E, cg3.w, 1.f)), a3);
    }
    {
        float* accs = smem;                      // [uq][q][e]
        accs[((uq << 2) + 0) * 256 + e] = a0;
        accs[((uq << 2) + 1) * 256 + e] = a1;
        accs[((uq << 2) + 2) * 256 + e] = a2;
        accs[((uq << 2) + 3) * 256 + e] = a3;
    }
    __syncthreads();

    // ---------------- softmax over e per q ----------------
    if (wv < 4) {
        const float* accs = smem;
        const int q = wv;
        float l[4];
        float m = -1e30f;
#pragma unroll
        for (int i = 0; i < 4; ++i) {
            int ee = lane + (i << 6);
            float a = accs[(0 + q) * 256 + ee] + accs[(4 + q) * 256 + ee] +
                      accs[(8 + q) * 256 + ee] + accs[(12 + q) * 256 + ee];
            l[i] = -2.f * a;
            m = fmaxf(m, l[i]);
        }
#pragma unroll
        for (int mk = 32; mk >= 1; mk >>= 1) m = fmaxf(m, __shfl_xor(m, mk, 64));
        float p[4];
        float s = 0.f;
#pragma unroll
        for (int i = 0; i < 4; ++i) {
            p[i] = __builtin_amdgcn_exp2f((l[i] - m) * LOG2E);
            s += p[i];
        }
#pragma unroll
        for (int mk = 32; mk >= 1; mk >>= 1) s += __shfl_xor(s, mk, 64);
        float inv = __builtin_amdgcn_rcpf(s);
#pragma unroll
        for (int i = 0; i < 4; ++i) wT[lane + (i << 6)][q] = p[i] * inv;
    }
    __syncthreads();

    // ---------------- context, 1x enc read ----------------
    {
        const int dp = tid & 255;                // d-pair
        const int d2 = dp << 1;
        float p0x = 0.f, p0y = 0.f, p1x = 0.f, p1y = 0.f;
        float p2x = 0.f, p2y = 0.f, p3x = 0.f, p3y = 0.f;
        const float* ep = enc + (((size_t)(b << 8) + (uq << 6)) << 9) + d2;
#pragma unroll 4
        for (int ee = 0; ee < 64; ++ee) {
            float2 x = *(const float2*)(ep + ((size_t)ee << 9));
            float4 w = *(const float4*)&wT[(uq << 6) + ee][0];   // wave-uniform
            p0x = fmaf(w.x, x.x, p0x); p0y = fmaf(w.x, x.y, p0y);
            p1x = fmaf(w.y, x.x, p1x); p1y = fmaf(w.y, x.y, p1y);
            p2x = fmaf(w.z, x.x, p2x); p2y = fmaf(w.z, x.y, p2y);
            p3x = fmaf(w.w, x.x, p3x); p3y = fmaf(w.w, x.y, p3y);
        }
        float2* sc = (float2*)smem;              // [eq][q][dp], 32 KB
        sc[((uq << 2) + 0) * 256 + dp] = make_float2(p0x, p0y);
        sc[((uq << 2) + 1) * 256 + dp] = make_float2(p1x, p1y);
        sc[((uq << 2) + 2) * 256 + dp] = make_float2(p2x, p2y);
        sc[((uq << 2) + 3) * 256 + dp] = make_float2(p3x, p3y);
        __syncthreads();
        const int q = uq;                        // tid>>8
        float2 s0 = sc[(0 + q) * 256 + dp];
        float2 s1 = sc[(4 + q) * 256 + dp];
        float2 s2 = sc[(8 + q) * 256 + dp];
        float2 s3 = sc[(12 + q) * 256 + dp];
        float2 o = make_float2(s0.x + s1.x + s2.x + s3.x,
                               s0.y + s1.y + s2.y + s3.y);
        *(float2*)&out[((size_t)((b << 7) + q0 + q) << 9) + d2] = o;
    }
}

// ---------------------------------------------------------------------------
extern "C" void kernel_launch(void* const* d_in, const int* in_sizes, int n_in,
                              void* d_out, int out_size, void* d_ws, size_t ws_size,
                              hipStream_t stream) {
    const float* enc      = (const float*)d_in[0];
    const float* dec      = (const float*)d_in[1];
    const float* Wenc     = (const float*)d_in[2];
    const float* Wdec     = (const float*)d_in[3];
    const float* Wscore   = (const float*)d_in[4];
    const float* bias_enc = (const float*)d_in[5];
    const float* bias_dec = (const float*)d_in[6];
    // d_in[7] = bias_score: constant shift, cancelled by softmax.
    float* out = (float*)d_out;

    float* ws = (float*)d_ws;
    float* d_encT4 = ws;                               // 1,048,576 floats (4 MB)
    float* Gt      = ws + 1048576;                     // 524,288 floats (2 MB)
    unsigned short* Weh = (unsigned short*)(ws + 1048576 + 524288);
    unsigned short* Wel = Weh + 262144;                // 4 x 512 KB = 2 MB
    unsigned short* Wdh = Wel + 262144;
    unsigned short* Wdl = Wdh + 262144;                // total ws use: 8 MB

    prep_w<<<128, 256, 0, stream>>>(Wenc, Wdec, Weh, Wel, Wdh, Wdl);
    proj_kernel<<<384, 256, 0, stream>>>(enc, dec, Weh, Wel, Wdh, Wdl,
                                         bias_enc, bias_dec, d_encT4, Gt);
    attend_kernel<<<256, 1024, 0, stream>>>(enc, d_encT4, Gt, Wscore, out);
}